// Round 6
// baseline (260.058 us; speedup 1.0000x reference)
//
#include <hip/hip_runtime.h>
#include <cstdint>
#include <cstddef>

#define N1 4096
#define N2 16384
#define C1 256
#define C2 128
#define HH 256
#define K1 384
#define BQ 32768          // B*N2 total queries
#define KPAD 392          // LDS k-stride (bf16 elems): 16B-aligned, banks balanced
#define NC 20             // grid cells per axis
#define NC3 8000          // NC^3
#define CW 0.5f           // cell width (exact in fp32)
#define GMIN (-5.0f)
#define MARG 4.0e-3f      // conservative pruning margin (>> 2e-4 worst rounding)

typedef float  f32x4  __attribute__((ext_vector_type(4)));
typedef __bf16 bf16x8 __attribute__((ext_vector_type(8)));
typedef __bf16 bf16x4 __attribute__((ext_vector_type(4)));

__device__ __forceinline__ int cell_of(float v) {
  int c = (int)floorf((v - GMIN) * 2.0f);
  return min(max(c, 0), NC - 1);
}

// Lexicographic (d, idx) insert == stable top-k semantics (ties -> lower idx).
#define LEXINS(da, db, dc, ia, ib, ic, dd, jj)                                 \
  {                                                                            \
    bool ca = ((dd) < (da)) || ((dd) == (da) && (jj) < (ia));                  \
    bool cb = ((dd) < (db)) || ((dd) == (db) && (jj) < (ib));                  \
    bool cc = ((dd) < (dc)) || ((dd) == (dc) && (jj) < (ic));                  \
    dc = cb ? (db) : (cc ? (dd) : (dc));                                       \
    ic = cb ? (ib) : (cc ? (jj) : (ic));                                       \
    db = ca ? (da) : (cb ? (dd) : (db));                                       \
    ib = ca ? (ia) : (cb ? (jj) : (ib));                                       \
    da = ca ? (dd) : (da);                                                     \
    ia = ca ? (jj) : (ia);                                                     \
  }

// ---------------------------------------------------------------------------
// k_zero: clear per-cell counters.
// ---------------------------------------------------------------------------
__global__ __launch_bounds__(256) void k_zero(unsigned* __restrict__ cellcnt) {
  int i = blockIdx.x * 256 + threadIdx.x;
  if (i < 2 * NC3) cellcnt[i] = 0u;
}

// ---------------------------------------------------------------------------
// k_prep: pts4 = (x,y,z,|k|^2) exact RN; cell id + count per cell; W1/W2 ->
// bf16; BN folded to per-row scale/shift.
// ---------------------------------------------------------------------------
__global__ __launch_bounds__(256) void k_prep(
    const float* __restrict__ p1,
    const float* __restrict__ W1, const float* __restrict__ W2,
    const float* __restrict__ b1, const float* __restrict__ g1,
    const float* __restrict__ be1, const float* __restrict__ mm1,
    const float* __restrict__ vv1,
    const float* __restrict__ b2, const float* __restrict__ g2,
    const float* __restrict__ be2, const float* __restrict__ mm2,
    const float* __restrict__ vv2,
    float4* __restrict__ pts4, unsigned short* __restrict__ cellid,
    unsigned* __restrict__ cellcnt,
    __bf16* __restrict__ W1b, __bf16* __restrict__ W2b,
    float* __restrict__ scsh) {
  int idx = blockIdx.x * 256 + threadIdx.x;      // grid 384*256 = 98304
  if (idx < HH * K1) W1b[idx] = (__bf16)W1[idx];
  if (idx < HH * HH) W2b[idx] = (__bf16)W2[idx];
  if (idx < 2 * N1) {
    int b = idx >> 12, j = idx & (N1 - 1);
    const float* p = p1 + (size_t)b * 3 * N1;
    float x = p[j], y = p[N1 + j], z = p[2 * N1 + j];
    float sk = __fadd_rn(__fadd_rn(__fmul_rn(x, x), __fmul_rn(y, y)),
                         __fmul_rn(z, z));
    pts4[idx] = make_float4(x, y, z, sk);
    int cid = (cell_of(z) * NC + cell_of(y)) * NC + cell_of(x);
    cellid[idx] = (unsigned short)cid;
    atomicAdd(&cellcnt[b * NC3 + cid], 1u);
  }
  if (idx < HH) {
    float sc = g1[idx] / sqrtf(vv1[idx] + 1e-3f);
    scsh[idx]          = sc;
    scsh[HH + idx]     = fmaf(b1[idx] - mm1[idx], sc, be1[idx]);
    float s2 = g2[idx] / sqrtf(vv2[idx] + 1e-3f);
    scsh[2 * HH + idx] = s2;
    scsh[3 * HH + idx] = fmaf(b2[idx] - mm2[idx], s2, be2[idx]);
  }
}

// ---------------------------------------------------------------------------
// k_scan: exclusive prefix sum over the 8000 cells of one batch (1 block per
// batch). celltab packs (cnt<<16)|ofs; cursor gets the running offsets for
// the scatter pass.
// ---------------------------------------------------------------------------
__global__ __launch_bounds__(1024) void k_scan(
    const unsigned* __restrict__ cellcnt, unsigned* __restrict__ celltab,
    unsigned* __restrict__ cursor) {
  __shared__ unsigned ssum[1024];
  const int b = blockIdx.x, t = threadIdx.x;
  const unsigned* cc = cellcnt + b * NC3;
  unsigned c[8], s = 0;
  int base = t * 8;
#pragma unroll
  for (int j = 0; j < 8; ++j) {
    unsigned v = (base + j < NC3) ? cc[base + j] : 0u;
    c[j] = v; s += v;
  }
  ssum[t] = s;
  __syncthreads();
  for (int off = 1; off < 1024; off <<= 1) {
    unsigned v = (t >= off) ? ssum[t - off] : 0u;
    __syncthreads();
    ssum[t] += v;
    __syncthreads();
  }
  unsigned excl = ssum[t] - s;
#pragma unroll
  for (int j = 0; j < 8; ++j) {
    if (base + j < NC3) {
      celltab[b * NC3 + base + j] = (c[j] << 16) | excl;
      cursor[b * NC3 + base + j] = excl;
      excl += c[j];
    }
  }
}

// ---------------------------------------------------------------------------
// k_scatter: cell-sort points (order within a cell is atomic-nondeterministic;
// harmless — the query kernel computes a set-min via LEXINS).
// ---------------------------------------------------------------------------
__global__ __launch_bounds__(256) void k_scatter(
    const float4* __restrict__ pts4, const unsigned short* __restrict__ cellid,
    unsigned* __restrict__ cursor, float4* __restrict__ spts,
    unsigned short* __restrict__ sidx) {
  int idx = blockIdx.x * 256 + threadIdx.x;      // 32 blocks
  if (idx >= 2 * N1) return;
  int b = idx >> 12;
  unsigned cid = cellid[idx];
  unsigned pos = atomicAdd(&cursor[b * NC3 + cid], 1u);
  spts[b * N1 + pos] = pts4[idx];
  sidx[b * N1 + pos] = (unsigned short)(idx & (N1 - 1));
}

// ---------------------------------------------------------------------------
// k_nn: exact grid 3-NN + reference weight arithmetic.
// 4 lanes per query (stride-4 candidate split, coalesced 64B pack loads).
// Chebyshev rings with conservative pruning:
//   ring break  iff ((R-1)*CW)^2        > prune + MARG
//   cell skip   iff box-distance^2 (bb) > prune + MARG
// prune = pack-min of per-lane 3rd-best (>= final dc) -> pack-uniform control
// flow (shuffles never touch exited lanes). Candidate dd uses the EXACT RN
// sequence of the reference; LEXINS reproduces stable top-k bit-exactly.
// ---------------------------------------------------------------------------
__global__ __launch_bounds__(256) void k_nn(
    const float* __restrict__ p2, const float4* __restrict__ spts,
    const unsigned short* __restrict__ sidx,
    const unsigned* __restrict__ celltab,
    float* __restrict__ wbuf, int* __restrict__ ibuf) {
#pragma clang fp contract(off)
  const int tid = threadIdx.x;
  const int sub = tid & 3;
  const int ql = blockIdx.x * 64 + (tid >> 2);   // 512 blocks -> 32768 queries
  const int b  = ql >> 14;
  const int n  = ql & (N2 - 1);

  const float* p2b = p2 + (size_t)b * 3 * N2;
  float ux = p2b[n], uy = p2b[N2 + n], uz = p2b[2 * N2 + n];
  float su = __fadd_rn(__fadd_rn(__fmul_rn(ux, ux), __fmul_rn(uy, uy)),
                       __fmul_rn(uz, uz));

  const int icx = cell_of(ux), icy = cell_of(uy), icz = cell_of(uz);
  const float4* sp = spts + (size_t)b * N1;
  const unsigned short* si = sidx + (size_t)b * N1;
  const unsigned* ct = celltab + b * NC3;

  float da = 3.0e38f, db = 3.0e38f, dc = 3.0e38f;
  int ia = 0x7fffffff, ib = 0x7fffffff, ic = 0x7fffffff;
  float prune = 3.0e38f;

  for (int R = 0; R < 24; ++R) {
    if (R > 0) {
      float rb = (float)(R - 1) * CW;            // exact
      if (rb * rb > prune + MARG) break;
    }
    int zlo = max(icz - R, 0), zhi = min(icz + R, NC - 1);
    int ylo = max(icy - R, 0), yhi = min(icy + R, NC - 1);
    int xlo = max(icx - R, 0), xhi = min(icx + R, NC - 1);
    for (int cz = zlo; cz <= zhi; ++cz) {
      int adz = abs(cz - icz);
      for (int cy = ylo; cy <= yhi; ++cy) {
        int ady = abs(cy - icy);
        for (int cx = xlo; cx <= xhi; ++cx) {
          int cheb = max(max(abs(cx - icx), ady), adz);
          if (cheb != R) continue;               // ring only (no re-scans)
          unsigned e = ct[(cz * NC + cy) * NC + cx];
          unsigned cnt = e >> 16;
          if (!cnt) continue;
          unsigned ofs = e & 0xffffu;
          if (R > 0) {
            float lx = (float)cx * CW + GMIN;    // exact (multiples of 0.5)
            float ly = (float)cy * CW + GMIN;
            float lz = (float)cz * CW + GMIN;
            float dxv = fmaxf(fmaxf(lx - ux, ux - (lx + CW)), 0.0f);
            float dyv = fmaxf(fmaxf(ly - uy, uy - (ly + CW)), 0.0f);
            float dzv = fmaxf(fmaxf(lz - uz, uz - (lz + CW)), 0.0f);
            float bb = fmaf(dzv, dzv, fmaf(dyv, dyv, dxv * dxv));
            if (bb > prune + MARG) continue;
          }
          for (unsigned t2 = ofs + sub; t2 < ofs + cnt; t2 += 4) {
            float4 p = sp[t2];
            int jj = (int)si[t2];
            float dot = __fadd_rn(
                __fadd_rn(__fmul_rn(ux, p.x), __fmul_rn(uy, p.y)),
                __fmul_rn(uz, p.z));
            float dd = __builtin_fmaf(dot, -2.0f, __fadd_rn(su, p.w));
            LEXINS(da, db, dc, ia, ib, ic, dd, jj);
          }
        }
      }
    }
    float m1 = fminf(dc, __shfl_xor(dc, 1, 64));
    prune = fminf(m1, __shfl_xor(m1, 2, 64));
  }

  // merge the 4 per-lane partials (set-min; order-independent)
#pragma unroll
  for (int m = 1; m <= 2; m <<= 1) {
    float ea = __shfl_xor(da, m, 64), eb = __shfl_xor(db, m, 64),
          ec = __shfl_xor(dc, m, 64);
    int ja = __shfl_xor(ia, m, 64), jb = __shfl_xor(ib, m, 64),
        jc = __shfl_xor(ic, m, 64);
    LEXINS(da, db, dc, ia, ib, ic, ea, ja);
    LEXINS(da, db, dc, ia, ib, ic, eb, jb);
    LEXINS(da, db, dc, ia, ib, ic, ec, jc);
  }

  if (sub == 0) {
    float qa = fmaxf(da, 0.0f), qb = fmaxf(db, 0.0f), qc = fmaxf(dc, 0.0f);
    qa = fmaxf(__fmul_rn(qa, qa), 1e-10f);
    qb = fmaxf(__fmul_rn(qb, qb), 1e-10f);
    qc = fmaxf(__fmul_rn(qc, qc), 1e-10f);
    float va = __fdiv_rn(1.0f, qa);
    float vb = __fdiv_rn(1.0f, qb);
    float vc = __fdiv_rn(1.0f, qc);
    float s = __fadd_rn(__fadd_rn(va, vb), vc);
    int q = b * N2 + n;
    wbuf[q]          = __fdiv_rn(va, s);
    wbuf[BQ + q]     = __fdiv_rn(vb, s);
    wbuf[2 * BQ + q] = __fdiv_rn(vc, s);
    ibuf[q]          = ia;
    ibuf[BQ + q]     = ib;
    ibuf[2 * BQ + q] = ic;
  }
}

// ---------------------------------------------------------------------------
// k_transpose: features1 [B,C1,N1] -> f1T [B,N1,C1] (contiguous gather rows).
// ---------------------------------------------------------------------------
__global__ __launch_bounds__(256) void k_transpose(
    const float* __restrict__ f1, float* __restrict__ f1T) {
  __shared__ float tile[64][65];
  const int bx = blockIdx.x;            // B * 4(ct) * 64(nt) = 512
  const int b = bx >> 8;
  const int rest = bx & 255;
  const int ct = rest >> 6;
  const int ntb = (rest & 63) << 6;
  const int t = threadIdx.x;
  const int ln = t & 63, g = t >> 6;

  const float* src = f1 + ((size_t)b * C1 + ct * 64) * N1 + ntb;
  for (int k = 0; k < 16; ++k) {
    int c = (k << 2) + g;
    tile[c][ln] = src[(size_t)c * N1 + ln];
  }
  __syncthreads();
  float* dst = f1T + ((size_t)b * N1 + ntb) * C1 + ct * 64;
  for (int k = 0; k < 16; ++k) {
    int nn = (k << 2) + g;
    dst[(size_t)nn * C1 + ln] = tile[ln][nn];
  }
}

// ---------------------------------------------------------------------------
// k_fused: gather+interp -> bf16 LDS [col][k] -> MFMA GEMM1 -> BN1+ReLU ->
// bf16 LDS h -> MFMA GEMM2 -> BN2+ReLU -> out (fp32).
// 256 threads = 4 waves; wave wv owns output rows [wv*64, wv*64+64), all 64
// cols of the block's n-tile: 4x4 tiles of mfma_f32_16x16x32_bf16.
// ---------------------------------------------------------------------------
__global__ __launch_bounds__(256) void k_fused(
    const float* __restrict__ f1T, const float* __restrict__ f2,
    const float* __restrict__ wbuf, const int* __restrict__ ibuf,
    const __bf16* __restrict__ W1b, const __bf16* __restrict__ W2b,
    const float* __restrict__ scsh, float* __restrict__ out) {
  __shared__ __bf16 sX[64 * KPAD];       // 49KB; x for GEMM1, then h for GEMM2
  const int t = threadIdx.x;
  const int bx = blockIdx.x;
  const int b = bx >> 8;
  const int n0 = (bx & 255) << 6;

  // ---- Phase A1: interp C1 channels (k = 0..255) ----
  {
    const int nn = t >> 2, qq = t & 3;   // 4 threads per column
    const int gi = b * N2 + n0 + nn;
    const float w0 = wbuf[gi], w1 = wbuf[BQ + gi], w2 = wbuf[2 * BQ + gi];
    const int i0 = ibuf[gi], i1 = ibuf[BQ + gi], i2 = ibuf[2 * BQ + gi];
    const float4* r0 = (const float4*)(f1T + ((size_t)b * N1 + i0) * C1);
    const float4* r1 = (const float4*)(f1T + ((size_t)b * N1 + i1) * C1);
    const float4* r2 = (const float4*)(f1T + ((size_t)b * N1 + i2) * C1);
#pragma unroll 4
    for (int m = 0; m < 16; ++m) {
      int idx4 = (qq << 4) + m;
      float4 a = r0[idx4], c4 = r1[idx4], d4 = r2[idx4];
      bf16x4 v;
      v[0] = (__bf16)fmaf(w0, a.x, fmaf(w1, c4.x, w2 * d4.x));
      v[1] = (__bf16)fmaf(w0, a.y, fmaf(w1, c4.y, w2 * d4.y));
      v[2] = (__bf16)fmaf(w0, a.z, fmaf(w1, c4.z, w2 * d4.z));
      v[3] = (__bf16)fmaf(w0, a.w, fmaf(w1, c4.w, w2 * d4.w));
      *(bf16x4*)&sX[nn * KPAD + (idx4 << 2)] = v;
    }
  }
  // ---- Phase A2: features2 channels (k = 256..383) ----
  {
    const int col = t & 63, g = t >> 6;
    const float* f2b = f2 + (size_t)b * C2 * N2 + n0 + col;
#pragma unroll 2
    for (int m = 0; m < 8; ++m) {
      int c4 = (g << 5) + (m << 2);
      bf16x4 v;
      v[0] = (__bf16)f2b[(size_t)(c4 + 0) * N2];
      v[1] = (__bf16)f2b[(size_t)(c4 + 1) * N2];
      v[2] = (__bf16)f2b[(size_t)(c4 + 2) * N2];
      v[3] = (__bf16)f2b[(size_t)(c4 + 3) * N2];
      *(bf16x4*)&sX[col * KPAD + 256 + c4] = v;
    }
  }
  __syncthreads();

  const int l  = t & 63;
  const int wv = __builtin_amdgcn_readfirstlane(t >> 6);
  const int ob = wv << 6;
  const int lm = l & 15, lg = l >> 4;

  f32x4 acc[4][4];
#pragma unroll
  for (int mt = 0; mt < 4; ++mt)
#pragma unroll
    for (int nt = 0; nt < 4; ++nt) acc[mt][nt] = (f32x4)0.0f;

  // ---- GEMM1: K = 384 (12 k-steps) ----
  for (int ks = 0; ks < 12; ++ks) {
    bf16x8 af[4], bfr[4];
#pragma unroll
    for (int mt = 0; mt < 4; ++mt)
      af[mt] = *(const bf16x8*)(W1b + (size_t)(ob + mt * 16 + lm) * K1 +
                                ks * 32 + lg * 8);
#pragma unroll
    for (int nt = 0; nt < 4; ++nt)
      bfr[nt] = *(const bf16x8*)&sX[(nt * 16 + lm) * KPAD + ks * 32 + lg * 8];
#pragma unroll
    for (int mt = 0; mt < 4; ++mt)
#pragma unroll
      for (int nt = 0; nt < 4; ++nt)
        acc[mt][nt] = __builtin_amdgcn_mfma_f32_16x16x32_bf16(
            af[mt], bfr[nt], acc[mt][nt], 0, 0, 0);
  }
  __syncthreads();

  // ---- BN1 + ReLU -> h (bf16) back into sX ----
#pragma unroll
  for (int mt = 0; mt < 4; ++mt) {
    int rb = ob + mt * 16 + lg * 4;     // h-channel base (GEMM1 output row)
    float4 sc4 = *(const float4*)(scsh + rb);
    float4 sh4 = *(const float4*)(scsh + HH + rb);
#pragma unroll
    for (int nt = 0; nt < 4; ++nt) {
      int colc = nt * 16 + lm;
      bf16x4 v;
      v[0] = (__bf16)fmaxf(fmaf(acc[mt][nt][0], sc4.x, sh4.x), 0.0f);
      v[1] = (__bf16)fmaxf(fmaf(acc[mt][nt][1], sc4.y, sh4.y), 0.0f);
      v[2] = (__bf16)fmaxf(fmaf(acc[mt][nt][2], sc4.z, sh4.z), 0.0f);
      v[3] = (__bf16)fmaxf(fmaf(acc[mt][nt][3], sc4.w, sh4.w), 0.0f);
      *(bf16x4*)&sX[colc * KPAD + rb] = v;
    }
  }
  __syncthreads();

  // ---- GEMM2: K = 256 (8 k-steps) ----
  f32x4 ac2[4][4];
#pragma unroll
  for (int mt = 0; mt < 4; ++mt)
#pragma unroll
    for (int nt = 0; nt < 4; ++nt) ac2[mt][nt] = (f32x4)0.0f;
  for (int ks = 0; ks < 8; ++ks) {
    bf16x8 af[4], bfr[4];
#pragma unroll
    for (int mt = 0; mt < 4; ++mt)
      af[mt] = *(const bf16x8*)(W2b + (size_t)(ob + mt * 16 + lm) * HH +
                                ks * 32 + lg * 8);
#pragma unroll
    for (int nt = 0; nt < 4; ++nt)
      bfr[nt] = *(const bf16x8*)&sX[(nt * 16 + lm) * KPAD + ks * 32 + lg * 8];
#pragma unroll
    for (int mt = 0; mt < 4; ++mt)
#pragma unroll
      for (int nt = 0; nt < 4; ++nt)
        ac2[mt][nt] = __builtin_amdgcn_mfma_f32_16x16x32_bf16(
            af[mt], bfr[nt], ac2[mt][nt], 0, 0, 0);
  }

  // ---- BN2 + ReLU -> out (fp32) ----
  float* outb = out + (size_t)b * HH * N2 + n0;
#pragma unroll
  for (int mt = 0; mt < 4; ++mt) {
    int rb = ob + mt * 16 + lg * 4;
    float4 sc4 = *(const float4*)(scsh + 2 * HH + rb);
    float4 sh4 = *(const float4*)(scsh + 3 * HH + rb);
#pragma unroll
    for (int nt = 0; nt < 4; ++nt) {
      int colc = nt * 16 + lm;
      outb[(size_t)(rb + 0) * N2 + colc] =
          fmaxf(fmaf(ac2[mt][nt][0], sc4.x, sh4.x), 0.0f);
      outb[(size_t)(rb + 1) * N2 + colc] =
          fmaxf(fmaf(ac2[mt][nt][1], sc4.y, sh4.y), 0.0f);
      outb[(size_t)(rb + 2) * N2 + colc] =
          fmaxf(fmaf(ac2[mt][nt][2], sc4.z, sh4.z), 0.0f);
      outb[(size_t)(rb + 3) * N2 + colc] =
          fmaxf(fmaf(ac2[mt][nt][3], sc4.w, sh4.w), 0.0f);
    }
  }
}

// ---------------------------------------------------------------------------
extern "C" void kernel_launch(void* const* d_in, const int* in_sizes, int n_in,
                              void* d_out, int out_size, void* d_ws, size_t ws_size,
                              hipStream_t stream) {
  const float* p1  = (const float*)d_in[0];
  const float* p2  = (const float*)d_in[1];
  const float* f1  = (const float*)d_in[2];
  const float* f2  = (const float*)d_in[3];
  const float* W1  = (const float*)d_in[4];
  const float* bb1 = (const float*)d_in[5];
  const float* g1  = (const float*)d_in[6];
  const float* be1 = (const float*)d_in[7];
  const float* mm1 = (const float*)d_in[8];
  const float* vv1 = (const float*)d_in[9];
  const float* W2  = (const float*)d_in[10];
  const float* bb2 = (const float*)d_in[11];
  const float* g2  = (const float*)d_in[12];
  const float* be2 = (const float*)d_in[13];
  const float* mm2 = (const float*)d_in[14];
  const float* vv2 = (const float*)d_in[15];
  float* out = (float*)d_out;

  // ws layout (~10.0 MB, no aliasing)
  char* ws = (char*)d_ws;
  float*          f1T     = (float*)(ws);                  // 8,388,608
  float*          wbuf    = (float*)(ws + 8388608);        //   393,216
  int*            ibuf    = (int*)  (ws + 8781824);        //   393,216
  float4*         pts4    = (float4*)(ws + 9175040);       //   131,072
  float4*         spts    = (float4*)(ws + 9306112);       //   131,072
  unsigned short* sidx    = (unsigned short*)(ws + 9437184);   // 16,384
  unsigned short* cellid  = (unsigned short*)(ws + 9453568);   // 16,384
  unsigned*       cellcnt = (unsigned*)(ws + 9469952);     //    64,000
  unsigned*       celltab = (unsigned*)(ws + 9533952);     //    64,000
  unsigned*       cursor  = (unsigned*)(ws + 9597952);     //    64,000
  __bf16*         W1b     = (__bf16*)(ws + 9661952);       //   196,608
  __bf16*         W2b     = (__bf16*)(ws + 9858560);       //   131,072
  float*          scsh    = (float*)(ws + 9989632);        //     4,096

  k_zero<<<63, 256, 0, stream>>>(cellcnt);
  k_prep<<<384, 256, 0, stream>>>(p1, W1, W2,
                                  bb1, g1, be1, mm1, vv1,
                                  bb2, g2, be2, mm2, vv2,
                                  pts4, cellid, cellcnt, W1b, W2b, scsh);
  k_scan<<<2, 1024, 0, stream>>>(cellcnt, celltab, cursor);
  k_scatter<<<32, 256, 0, stream>>>(pts4, cellid, cursor, spts, sidx);
  k_nn<<<512, 256, 0, stream>>>(p2, spts, sidx, celltab, wbuf, ibuf);
  k_transpose<<<512, 256, 0, stream>>>(f1, f1T);
  k_fused<<<512, 256, 0, stream>>>(f1T, f2, wbuf, ibuf, W1b, W2b, scsh, out);
}

// Round 7
// 125.735 us; speedup vs baseline: 2.0683x; 2.0683x over previous
//
#include <hip/hip_runtime.h>
#include <cstdint>
#include <cstddef>

#define N1 4096
#define N2 16384
#define C1 256
#define C2 128
#define HH 256
#define K1 384
#define BQ 32768          // B*N2 total queries
#define KPAD 392          // LDS k-stride (bf16 elems): 16B-aligned, banks balanced
#define NCH 16            // k_nn point chunks (256 points each)

typedef float  f32x4  __attribute__((ext_vector_type(4)));
typedef float  f32x2  __attribute__((ext_vector_type(2)));
typedef __bf16 bf16x8 __attribute__((ext_vector_type(8)));
typedef __bf16 bf16x4 __attribute__((ext_vector_type(4)));

// Exact reference RN sequence for squared distance:
// dot = rn(rn(rn(ux*px)+rn(uy*py))+rn(uz*pz));
// dd  = rn(rn(su+pw) - 2*dot)   [-2*dot exact -> fmaf equals the 2-op form]
__device__ __forceinline__ float exact_dd(float ux, float uy, float uz,
                                          float su, float4 p) {
  float dot = __fadd_rn(__fadd_rn(__fmul_rn(ux, p.x), __fmul_rn(uy, p.y)),
                        __fmul_rn(uz, p.z));
  return __builtin_fmaf(dot, -2.0f, __fadd_rn(su, p.w));
}

// Lexicographic (d, idx) insert == stable top-k semantics (ties -> lower idx).
#define LEXINS(da, db, dc, ia, ib, ic, dd, jj)                                 \
  {                                                                            \
    bool ca = ((dd) < (da)) || ((dd) == (da) && (jj) < (ia));                  \
    bool cb = ((dd) < (db)) || ((dd) == (db) && (jj) < (ib));                  \
    bool cc = ((dd) < (dc)) || ((dd) == (dc) && (jj) < (ic));                  \
    dc = cb ? (db) : (cc ? (dd) : (dc));                                       \
    ic = cb ? (ib) : (cc ? (jj) : (ic));                                       \
    db = ca ? (da) : (cb ? (dd) : (db));                                       \
    ib = ca ? (ia) : (cb ? (jj) : (ib));                                       \
    da = ca ? (dd) : (da);                                                     \
    ia = ca ? (jj) : (ia);                                                     \
  }

// Sorted top-4 maintain on float keys: 1 min + 3 med3 (indices ride in the
// low 12 bits of the key, so no cndmask chains needed).
#define KMIN4(K1_, K2_, K3_, K4_, x)                                           \
  {                                                                            \
    float n1 = fminf((K1_), (x));                                              \
    float n2 = __builtin_amdgcn_fmed3f((K1_), (x), (K2_));                     \
    float n3 = __builtin_amdgcn_fmed3f((K2_), (x), (K3_));                     \
    float n4 = __builtin_amdgcn_fmed3f((K3_), (x), (K4_));                     \
    K1_ = n1; K2_ = n2; K3_ = n3; K4_ = n4;                                    \
  }

// ---------------------------------------------------------------------------
// k_prep: pts8 pair-SoA [x0 x1 y0 y1 z0 z1 w0 w1] (packed math in k_nn) and
// plain pts4 (gather in k_merge), both with exact RN |k|^2; W1/W2 -> bf16;
// BN folded to per-row scale/shift.
// ---------------------------------------------------------------------------
__global__ __launch_bounds__(256) void k_prep(
    const float* __restrict__ p1,
    const float* __restrict__ W1, const float* __restrict__ W2,
    const float* __restrict__ b1, const float* __restrict__ g1,
    const float* __restrict__ be1, const float* __restrict__ mm1,
    const float* __restrict__ vv1,
    const float* __restrict__ b2, const float* __restrict__ g2,
    const float* __restrict__ be2, const float* __restrict__ mm2,
    const float* __restrict__ vv2,
    float* __restrict__ pts8, float4* __restrict__ pts4,
    __bf16* __restrict__ W1b, __bf16* __restrict__ W2b,
    float* __restrict__ scsh) {
  int idx = blockIdx.x * 256 + threadIdx.x;      // grid 384*256 = 98304
  if (idx < HH * K1) W1b[idx] = (__bf16)W1[idx];
  if (idx < HH * HH) W2b[idx] = (__bf16)W2[idx];
  if (idx < 2 * N1) {
    int b = idx >> 12, j = idx & (N1 - 1);
    const float* p = p1 + (size_t)b * 3 * N1;
    float x = p[j], y = p[N1 + j], z = p[2 * N1 + j];
    float sk = __fadd_rn(__fadd_rn(__fmul_rn(x, x), __fmul_rn(y, y)),
                         __fmul_rn(z, z));
    size_t base = ((size_t)b * (N1 / 2) + (j >> 1)) * 8 + (j & 1);
    pts8[base + 0] = x;
    pts8[base + 2] = y;
    pts8[base + 4] = z;
    pts8[base + 6] = sk;
    pts4[idx] = make_float4(x, y, z, sk);
  }
  if (idx < HH) {
    float sc = g1[idx] / sqrtf(vv1[idx] + 1e-3f);
    scsh[idx]          = sc;
    scsh[HH + idx]     = fmaf(b1[idx] - mm1[idx], sc, be1[idx]);
    float s2 = g2[idx] / sqrtf(vv2[idx] + 1e-3f);
    scsh[2 * HH + idx] = s2;
    scsh[3 * HH + idx] = fmaf(b2[idx] - mm2[idx], s2, be2[idx]);
  }
}

// ---------------------------------------------------------------------------
// k_nn: keyed brute-force 3-NN partials.
// 2048 blocks = 128 query-tiles x 16 point-chunks of 256 (round-4 proven
// occupancy shape). Per lane: packed-f32 distance (exact RN reference
// sequence), key = (dd_bits & ~0xFFF) | point_idx, sorted top-4 keys via
// min+med3 (4 ops, index tracking free). Keyed order == exact (d,idx) order
// except within 4096-ulp collision windows; those are caught by k_merge's
// flag and resolved exactly there.
// ---------------------------------------------------------------------------
__global__ __launch_bounds__(256) void k_nn(
    const float* __restrict__ p2, const float4* __restrict__ pts8,
    float* __restrict__ keybuf) {
#pragma clang fp contract(off)
  const int bx = blockIdx.x;
  const int ch = bx & (NCH - 1);
  const int qt = bx >> 4;            // 0..127
  const int b  = qt >> 6;            // uniform per block
  const int n  = ((qt & 63) << 8) + threadIdx.x;

  const float* p2b = p2 + (size_t)b * 3 * N2;
  float ux = p2b[n], uy = p2b[N2 + n], uz = p2b[2 * N2 + n];
  float su = __fadd_rn(__fadd_rn(__fmul_rn(ux, ux), __fmul_rn(uy, uy)),
                       __fmul_rn(uz, uz));
  f32x2 uxv = {ux, ux}, uyv = {uy, uy}, uzv = {uz, uz}, suv = {su, su};
  const f32x2 ntwo = {-2.0f, -2.0f};

  // pair-SoA: 2 float4 per point-pair; chunk = 128 pairs
  const float4* pp = pts8 + ((size_t)b * (N1 / 2) + ch * 128) * 2;
  const int j0 = ch * 256;
  float Ka = 3.0e38f, Kb = 3.0e38f, Kc = 3.0e38f, Kd = 3.0e38f;
#pragma unroll 4
  for (int k = 0; k < 128; ++k) {
    float4 q0 = pp[2 * k];           // x0 x1 y0 y1
    float4 q1 = pp[2 * k + 1];       // z0 z1 w0 w1
    f32x2 X = {q0.x, q0.y}, Y = {q0.z, q0.w};
    f32x2 Z = {q1.x, q1.y}, Wp = {q1.z, q1.w};
    f32x2 dot = (uxv * X + uyv * Y) + uzv * Z;
    f32x2 spw = suv + Wp;
    f32x2 dd2 = dot * ntwo + spw;    // == rn(spw - 2*dot), product exact
    unsigned u0 = (__float_as_uint(dd2[0]) & 0xFFFFF000u) |
                  (unsigned)(j0 + 2 * k);
    float x0 = __uint_as_float(u0);
    KMIN4(Ka, Kb, Kc, Kd, x0);
    unsigned u1 = (__float_as_uint(dd2[1]) & 0xFFFFF000u) |
                  (unsigned)(j0 + 2 * k + 1);
    float x1 = __uint_as_float(u1);
    KMIN4(Ka, Kb, Kc, Kd, x1);
  }

  // dense [plane][q] layout: coalesced, no write amplification
  int q = b * N2 + n;
  keybuf[(ch * 4 + 0) * BQ + q] = Ka;
  keybuf[(ch * 4 + 1) * BQ + q] = Kb;
  keybuf[(ch * 4 + 2) * BQ + q] = Kc;
  keybuf[(ch * 4 + 3) * BQ + q] = Kd;
}

// ---------------------------------------------------------------------------
// k_merge: fold 64 chunk keys -> global keyed top-4; flag if k3/k4 share the
// masked value bits (the only situation in which keyed selection can differ
// from exact stable top-3 — collision groups are contiguous in keyed order,
// so a set error forces a k3/k4 collision). Unflagged: indices from keys.
// Flagged (rare): exact (d,idx) LEXINS over the 64 candidates. Both paths
// recompute exact RN dd for the 3 selected points, then the exact reference
// weight arithmetic. Output is permutation-invariant over the 3 neighbors.
// ---------------------------------------------------------------------------
__global__ __launch_bounds__(256) void k_merge(
    const float* __restrict__ keybuf, const float4* __restrict__ pts4,
    const float* __restrict__ p2,
    float* __restrict__ wbuf, int* __restrict__ ibuf) {
#pragma clang fp contract(off)
  int q = blockIdx.x * 256 + threadIdx.x;    // 128 blocks
  int b = q >> 14, n = q & (N2 - 1);

  const float* p2b = p2 + (size_t)b * 3 * N2;
  float ux = p2b[n], uy = p2b[N2 + n], uz = p2b[2 * N2 + n];
  float su = __fadd_rn(__fadd_rn(__fmul_rn(ux, ux), __fmul_rn(uy, uy)),
                       __fmul_rn(uz, uz));

  float Ka = 3.0e38f, Kb = 3.0e38f, Kc = 3.0e38f, Kd = 3.0e38f;
#pragma unroll 8
  for (int i = 0; i < 4 * NCH; ++i) {
    float x = keybuf[i * BQ + q];
    KMIN4(Ka, Kb, Kc, Kd, x);
  }
  bool flag = (__float_as_uint(Kc) >> 12) == (__float_as_uint(Kd) >> 12);

  const float4* pb = pts4 + (size_t)b * N1;
  float da, db, dc;
  int ia, ib, ic;
  if (!flag) {
    ia = (int)(__float_as_uint(Ka) & 0xFFFu);
    ib = (int)(__float_as_uint(Kb) & 0xFFFu);
    ic = (int)(__float_as_uint(Kc) & 0xFFFu);
    da = exact_dd(ux, uy, uz, su, pb[ia]);
    db = exact_dd(ux, uy, uz, su, pb[ib]);
    dc = exact_dd(ux, uy, uz, su, pb[ic]);
  } else {
    da = 3.0e38f; db = 3.0e38f; dc = 3.0e38f;
    ia = 0x7fffffff; ib = 0x7fffffff; ic = 0x7fffffff;
    for (int i = 0; i < 4 * NCH; ++i) {
      float x = keybuf[i * BQ + q];
      int jj = (int)(__float_as_uint(x) & 0xFFFu);
      float dd = exact_dd(ux, uy, uz, su, pb[jj]);
      LEXINS(da, db, dc, ia, ib, ic, dd, jj);
    }
  }

  // exact reference weight arithmetic
  float qa = fmaxf(da, 0.0f), qb = fmaxf(db, 0.0f), qc = fmaxf(dc, 0.0f);
  qa = fmaxf(__fmul_rn(qa, qa), 1e-10f);
  qb = fmaxf(__fmul_rn(qb, qb), 1e-10f);
  qc = fmaxf(__fmul_rn(qc, qc), 1e-10f);
  float va = __fdiv_rn(1.0f, qa);
  float vb = __fdiv_rn(1.0f, qb);
  float vc = __fdiv_rn(1.0f, qc);
  float s = __fadd_rn(__fadd_rn(va, vb), vc);
  wbuf[q]           = __fdiv_rn(va, s);
  wbuf[BQ + q]      = __fdiv_rn(vb, s);
  wbuf[2 * BQ + q]  = __fdiv_rn(vc, s);
  ibuf[q]          = ia;
  ibuf[BQ + q]     = ib;
  ibuf[2 * BQ + q] = ic;
}

// ---------------------------------------------------------------------------
// k_transpose: features1 [B,C1,N1] -> f1T [B,N1,C1] (contiguous gather rows).
// NOTE: f1T aliases keybuf — must launch after k_merge.
// ---------------------------------------------------------------------------
__global__ __launch_bounds__(256) void k_transpose(
    const float* __restrict__ f1, float* __restrict__ f1T) {
  __shared__ float tile[64][65];
  const int bx = blockIdx.x;            // B * 4(ct) * 64(nt) = 512
  const int b = bx >> 8;
  const int rest = bx & 255;
  const int ct = rest >> 6;
  const int ntb = (rest & 63) << 6;
  const int t = threadIdx.x;
  const int ln = t & 63, g = t >> 6;

  const float* src = f1 + ((size_t)b * C1 + ct * 64) * N1 + ntb;
  for (int k = 0; k < 16; ++k) {
    int c = (k << 2) + g;
    tile[c][ln] = src[(size_t)c * N1 + ln];
  }
  __syncthreads();
  float* dst = f1T + ((size_t)b * N1 + ntb) * C1 + ct * 64;
  for (int k = 0; k < 16; ++k) {
    int nn = (k << 2) + g;
    dst[(size_t)nn * C1 + ln] = tile[ln][nn];
  }
}

// ---------------------------------------------------------------------------
// k_fused: gather+interp -> bf16 LDS [col][k] -> MFMA GEMM1 -> BN1+ReLU ->
// bf16 LDS h -> MFMA GEMM2 -> BN2+ReLU -> out (fp32).
// 256 threads = 4 waves; wave wv owns output rows [wv*64, wv*64+64), all 64
// cols of the block's n-tile: 4x4 tiles of mfma_f32_16x16x32_bf16.
// ---------------------------------------------------------------------------
__global__ __launch_bounds__(256) void k_fused(
    const float* __restrict__ f1T, const float* __restrict__ f2,
    const float* __restrict__ wbuf, const int* __restrict__ ibuf,
    const __bf16* __restrict__ W1b, const __bf16* __restrict__ W2b,
    const float* __restrict__ scsh, float* __restrict__ out) {
  __shared__ __bf16 sX[64 * KPAD];       // 49KB; x for GEMM1, then h for GEMM2
  const int t = threadIdx.x;
  const int bx = blockIdx.x;
  const int b = bx >> 8;
  const int n0 = (bx & 255) << 6;

  // ---- Phase A1: interp C1 channels (k = 0..255) ----
  {
    const int nn = t >> 2, qq = t & 3;   // 4 threads per column
    const int gi = b * N2 + n0 + nn;
    const float w0 = wbuf[gi], w1 = wbuf[BQ + gi], w2 = wbuf[2 * BQ + gi];
    const int i0 = ibuf[gi], i1 = ibuf[BQ + gi], i2 = ibuf[2 * BQ + gi];
    const float4* r0 = (const float4*)(f1T + ((size_t)b * N1 + i0) * C1);
    const float4* r1 = (const float4*)(f1T + ((size_t)b * N1 + i1) * C1);
    const float4* r2 = (const float4*)(f1T + ((size_t)b * N1 + i2) * C1);
#pragma unroll 4
    for (int m = 0; m < 16; ++m) {
      int idx4 = (qq << 4) + m;
      float4 a = r0[idx4], c4 = r1[idx4], d4 = r2[idx4];
      bf16x4 v;
      v[0] = (__bf16)fmaf(w0, a.x, fmaf(w1, c4.x, w2 * d4.x));
      v[1] = (__bf16)fmaf(w0, a.y, fmaf(w1, c4.y, w2 * d4.y));
      v[2] = (__bf16)fmaf(w0, a.z, fmaf(w1, c4.z, w2 * d4.z));
      v[3] = (__bf16)fmaf(w0, a.w, fmaf(w1, c4.w, w2 * d4.w));
      *(bf16x4*)&sX[nn * KPAD + (idx4 << 2)] = v;
    }
  }
  // ---- Phase A2: features2 channels (k = 256..383) ----
  {
    const int col = t & 63, g = t >> 6;
    const float* f2b = f2 + (size_t)b * C2 * N2 + n0 + col;
#pragma unroll 2
    for (int m = 0; m < 8; ++m) {
      int c4 = (g << 5) + (m << 2);
      bf16x4 v;
      v[0] = (__bf16)f2b[(size_t)(c4 + 0) * N2];
      v[1] = (__bf16)f2b[(size_t)(c4 + 1) * N2];
      v[2] = (__bf16)f2b[(size_t)(c4 + 2) * N2];
      v[3] = (__bf16)f2b[(size_t)(c4 + 3) * N2];
      *(bf16x4*)&sX[col * KPAD + 256 + c4] = v;
    }
  }
  __syncthreads();

  const int l  = t & 63;
  const int wv = __builtin_amdgcn_readfirstlane(t >> 6);
  const int ob = wv << 6;
  const int lm = l & 15, lg = l >> 4;

  f32x4 acc[4][4];
#pragma unroll
  for (int mt = 0; mt < 4; ++mt)
#pragma unroll
    for (int nt = 0; nt < 4; ++nt) acc[mt][nt] = (f32x4)0.0f;

  // ---- GEMM1: K = 384 (12 k-steps) ----
  for (int ks = 0; ks < 12; ++ks) {
    bf16x8 af[4], bfr[4];
#pragma unroll
    for (int mt = 0; mt < 4; ++mt)
      af[mt] = *(const bf16x8*)(W1b + (size_t)(ob + mt * 16 + lm) * K1 +
                                ks * 32 + lg * 8);
#pragma unroll
    for (int nt = 0; nt < 4; ++nt)
      bfr[nt] = *(const bf16x8*)&sX[(nt * 16 + lm) * KPAD + ks * 32 + lg * 8];
#pragma unroll
    for (int mt = 0; mt < 4; ++mt)
#pragma unroll
      for (int nt = 0; nt < 4; ++nt)
        acc[mt][nt] = __builtin_amdgcn_mfma_f32_16x16x32_bf16(
            af[mt], bfr[nt], acc[mt][nt], 0, 0, 0);
  }
  __syncthreads();

  // ---- BN1 + ReLU -> h (bf16) back into sX ----
#pragma unroll
  for (int mt = 0; mt < 4; ++mt) {
    int rb = ob + mt * 16 + lg * 4;     // h-channel base (GEMM1 output row)
    float4 sc4 = *(const float4*)(scsh + rb);
    float4 sh4 = *(const float4*)(scsh + HH + rb);
#pragma unroll
    for (int nt = 0; nt < 4; ++nt) {
      int colc = nt * 16 + lm;
      bf16x4 v;
      v[0] = (__bf16)fmaxf(fmaf(acc[mt][nt][0], sc4.x, sh4.x), 0.0f);
      v[1] = (__bf16)fmaxf(fmaf(acc[mt][nt][1], sc4.y, sh4.y), 0.0f);
      v[2] = (__bf16)fmaxf(fmaf(acc[mt][nt][2], sc4.z, sh4.z), 0.0f);
      v[3] = (__bf16)fmaxf(fmaf(acc[mt][nt][3], sc4.w, sh4.w), 0.0f);
      *(bf16x4*)&sX[colc * KPAD + rb] = v;
    }
  }
  __syncthreads();

  // ---- GEMM2: K = 256 (8 k-steps) ----
  f32x4 ac2[4][4];
#pragma unroll
  for (int mt = 0; mt < 4; ++mt)
#pragma unroll
    for (int nt = 0; nt < 4; ++nt) ac2[mt][nt] = (f32x4)0.0f;
  for (int ks = 0; ks < 8; ++ks) {
    bf16x8 af[4], bfr[4];
#pragma unroll
    for (int mt = 0; mt < 4; ++mt)
      af[mt] = *(const bf16x8*)(W2b + (size_t)(ob + mt * 16 + lm) * HH +
                                ks * 32 + lg * 8);
#pragma unroll
    for (int nt = 0; nt < 4; ++nt)
      bfr[nt] = *(const bf16x8*)&sX[(nt * 16 + lm) * KPAD + ks * 32 + lg * 8];
#pragma unroll
    for (int mt = 0; mt < 4; ++mt)
#pragma unroll
      for (int nt = 0; nt < 4; ++nt)
        ac2[mt][nt] = __builtin_amdgcn_mfma_f32_16x16x32_bf16(
            af[mt], bfr[nt], ac2[mt][nt], 0, 0, 0);
  }

  // ---- BN2 + ReLU -> out (fp32) ----
  float* outb = out + (size_t)b * HH * N2 + n0;
#pragma unroll
  for (int mt = 0; mt < 4; ++mt) {
    int rb = ob + mt * 16 + lg * 4;
    float4 sc4 = *(const float4*)(scsh + 2 * HH + rb);
    float4 sh4 = *(const float4*)(scsh + 3 * HH + rb);
#pragma unroll
    for (int nt = 0; nt < 4; ++nt) {
      int colc = nt * 16 + lm;
      outb[(size_t)(rb + 0) * N2 + colc] =
          fmaxf(fmaf(ac2[mt][nt][0], sc4.x, sh4.x), 0.0f);
      outb[(size_t)(rb + 1) * N2 + colc] =
          fmaxf(fmaf(ac2[mt][nt][1], sc4.y, sh4.y), 0.0f);
      outb[(size_t)(rb + 2) * N2 + colc] =
          fmaxf(fmaf(ac2[mt][nt][2], sc4.z, sh4.z), 0.0f);
      outb[(size_t)(rb + 3) * N2 + colc] =
          fmaxf(fmaf(ac2[mt][nt][3], sc4.w, sh4.w), 0.0f);
    }
  }
}

// ---------------------------------------------------------------------------
extern "C" void kernel_launch(void* const* d_in, const int* in_sizes, int n_in,
                              void* d_out, int out_size, void* d_ws, size_t ws_size,
                              hipStream_t stream) {
  const float* p1  = (const float*)d_in[0];
  const float* p2  = (const float*)d_in[1];
  const float* f1  = (const float*)d_in[2];
  const float* f2  = (const float*)d_in[3];
  const float* W1  = (const float*)d_in[4];
  const float* bb1 = (const float*)d_in[5];
  const float* g1  = (const float*)d_in[6];
  const float* be1 = (const float*)d_in[7];
  const float* mm1 = (const float*)d_in[8];
  const float* vv1 = (const float*)d_in[9];
  const float* W2  = (const float*)d_in[10];
  const float* bb2 = (const float*)d_in[11];
  const float* g2  = (const float*)d_in[12];
  const float* be2 = (const float*)d_in[13];
  const float* mm2 = (const float*)d_in[14];
  const float* vv2 = (const float*)d_in[15];
  float* out = (float*)d_out;

  // ws layout (~9.8 MB). keybuf lives only between k_nn and k_merge; the
  // same bytes are then reused for f1T (k_transpose launches after k_merge).
  char* ws = (char*)d_ws;
  float*  keybuf = (float*)(ws);                 // 8,388,608 B (= 64*BQ*4)
  float*  f1T    = (float*)(ws);                 // 8,388,608 B (alias)
  float*  wbuf   = (float*)(ws + 8388608);       //   393,216 B
  int*    ibuf   = (int*)  (ws + 8781824);       //   393,216 B
  float*  pts8   = (float*)(ws + 9175040);       //   131,072 B
  float4* pts4   = (float4*)(ws + 9306112);      //   131,072 B
  __bf16* W1b    = (__bf16*)(ws + 9437184);      //   196,608 B
  __bf16* W2b    = (__bf16*)(ws + 9633792);      //   131,072 B
  float*  scsh   = (float*)(ws + 9764864);       //     4,096 B

  k_prep<<<384, 256, 0, stream>>>(p1, W1, W2,
                                  bb1, g1, be1, mm1, vv1,
                                  bb2, g2, be2, mm2, vv2,
                                  pts8, pts4, W1b, W2b, scsh);
  k_nn<<<2048, 256, 0, stream>>>(p2, (const float4*)pts8, keybuf);
  k_merge<<<128, 256, 0, stream>>>(keybuf, pts4, p2, wbuf, ibuf);
  k_transpose<<<512, 256, 0, stream>>>(f1, f1T);   // reuses keybuf bytes
  k_fused<<<512, 256, 0, stream>>>(f1T, f2, wbuf, ibuf, W1b, W2b, scsh, out);
}

// Round 9
// 124.849 us; speedup vs baseline: 2.0830x; 1.0071x over previous
//
#include <hip/hip_runtime.h>
#include <cstdint>
#include <cstddef>

#define N1 4096
#define N2 16384
#define C1 256
#define C2 128
#define HH 256
#define K1 384
#define BQ 32768          // B*N2 total queries
#define KPAD 392          // LDS k-stride (bf16 elems): 16B-aligned, banks balanced
#define NCH 16            // k_nn point chunks (256 points each)

typedef float  f32x4  __attribute__((ext_vector_type(4)));
typedef float  f32x2  __attribute__((ext_vector_type(2)));
typedef __bf16 bf16x8 __attribute__((ext_vector_type(8)));
typedef __bf16 bf16x4 __attribute__((ext_vector_type(4)));

// Exact reference RN sequence for squared distance.
__device__ __forceinline__ float exact_dd(float ux, float uy, float uz,
                                          float su, float4 p) {
  float dot = __fadd_rn(__fadd_rn(__fmul_rn(ux, p.x), __fmul_rn(uy, p.y)),
                        __fmul_rn(uz, p.z));
  return __builtin_fmaf(dot, -2.0f, __fadd_rn(su, p.w));
}

// Lexicographic (d, idx) insert == stable top-k semantics (ties -> lower idx).
#define LEXINS(da, db, dc, ia, ib, ic, dd, jj)                                 \
  {                                                                            \
    bool ca = ((dd) < (da)) || ((dd) == (da) && (jj) < (ia));                  \
    bool cb = ((dd) < (db)) || ((dd) == (db) && (jj) < (ib));                  \
    bool cc = ((dd) < (dc)) || ((dd) == (dc) && (jj) < (ic));                  \
    dc = cb ? (db) : (cc ? (dd) : (dc));                                       \
    ic = cb ? (ib) : (cc ? (jj) : (ic));                                       \
    db = ca ? (da) : (cb ? (dd) : (db));                                       \
    ib = ca ? (ia) : (cb ? (jj) : (ib));                                       \
    da = ca ? (dd) : (da);                                                     \
    ia = ca ? (jj) : (ia);                                                     \
  }

// Sorted top-4 maintain on float keys: 1 min + 3 med3.
#define KMIN4(K1_, K2_, K3_, K4_, x)                                           \
  {                                                                            \
    float n1 = fminf((K1_), (x));                                              \
    float n2 = __builtin_amdgcn_fmed3f((K1_), (x), (K2_));                     \
    float n3 = __builtin_amdgcn_fmed3f((K2_), (x), (K3_));                     \
    float n4 = __builtin_amdgcn_fmed3f((K3_), (x), (K4_));                     \
    K1_ = n1; K2_ = n2; K3_ = n3; K4_ = n4;                                    \
  }

// ---------------------------------------------------------------------------
// k_prep: pts8 pair-SoA (packed math in k_nn) and plain pts4 (gather in
// k_merge), exact RN |k|^2; W1/W2 -> bf16; BN folded to scale/shift.
// ---------------------------------------------------------------------------
__global__ __launch_bounds__(256) void k_prep(
    const float* __restrict__ p1,
    const float* __restrict__ W1, const float* __restrict__ W2,
    const float* __restrict__ b1, const float* __restrict__ g1,
    const float* __restrict__ be1, const float* __restrict__ mm1,
    const float* __restrict__ vv1,
    const float* __restrict__ b2, const float* __restrict__ g2,
    const float* __restrict__ be2, const float* __restrict__ mm2,
    const float* __restrict__ vv2,
    float* __restrict__ pts8, float4* __restrict__ pts4,
    __bf16* __restrict__ W1b, __bf16* __restrict__ W2b,
    float* __restrict__ scsh) {
  int idx = blockIdx.x * 256 + threadIdx.x;      // grid 384*256 = 98304
  if (idx < HH * K1) W1b[idx] = (__bf16)W1[idx];
  if (idx < HH * HH) W2b[idx] = (__bf16)W2[idx];
  if (idx < 2 * N1) {
    int b = idx >> 12, j = idx & (N1 - 1);
    const float* p = p1 + (size_t)b * 3 * N1;
    float x = p[j], y = p[N1 + j], z = p[2 * N1 + j];
    float sk = __fadd_rn(__fadd_rn(__fmul_rn(x, x), __fmul_rn(y, y)),
                         __fmul_rn(z, z));
    size_t base = ((size_t)b * (N1 / 2) + (j >> 1)) * 8 + (j & 1);
    pts8[base + 0] = x;
    pts8[base + 2] = y;
    pts8[base + 4] = z;
    pts8[base + 6] = sk;
    pts4[idx] = make_float4(x, y, z, sk);
  }
  if (idx < HH) {
    float sc = g1[idx] / sqrtf(vv1[idx] + 1e-3f);
    scsh[idx]          = sc;
    scsh[HH + idx]     = fmaf(b1[idx] - mm1[idx], sc, be1[idx]);
    float s2 = g2[idx] / sqrtf(vv2[idx] + 1e-3f);
    scsh[2 * HH + idx] = s2;
    scsh[3 * HH + idx] = fmaf(b2[idx] - mm2[idx], s2, be2[idx]);
  }
}

// ---------------------------------------------------------------------------
// k_nn: keyed brute-force 3-NN partials (round-7 proven shape).
// key = bfi(0xFFFFF000, dd_bits, idx): (a&M)|(~M&b) pattern -> v_bfi_b32.
// ---------------------------------------------------------------------------
__global__ __launch_bounds__(256) void k_nn(
    const float* __restrict__ p2, const float4* __restrict__ pts8,
    float* __restrict__ keybuf) {
#pragma clang fp contract(off)
  const int bx = blockIdx.x;
  const int ch = bx & (NCH - 1);
  const int qt = bx >> 4;            // 0..127
  const int b  = qt >> 6;            // uniform per block
  const int n  = ((qt & 63) << 8) + threadIdx.x;

  const float* p2b = p2 + (size_t)b * 3 * N2;
  float ux = p2b[n], uy = p2b[N2 + n], uz = p2b[2 * N2 + n];
  float su = __fadd_rn(__fadd_rn(__fmul_rn(ux, ux), __fmul_rn(uy, uy)),
                       __fmul_rn(uz, uz));
  f32x2 uxv = {ux, ux}, uyv = {uy, uy}, uzv = {uz, uz}, suv = {su, su};
  const f32x2 ntwo = {-2.0f, -2.0f};

  const float4* pp = pts8 + ((size_t)b * (N1 / 2) + ch * 128) * 2;
  const int j0 = ch * 256;
  float Ka = 3.0e38f, Kb = 3.0e38f, Kc = 3.0e38f, Kd = 3.0e38f;
#pragma unroll 4
  for (int k = 0; k < 128; ++k) {
    float4 q0 = pp[2 * k];           // x0 x1 y0 y1
    float4 q1 = pp[2 * k + 1];       // z0 z1 w0 w1
    f32x2 X = {q0.x, q0.y}, Y = {q0.z, q0.w};
    f32x2 Z = {q1.x, q1.y}, Wp = {q1.z, q1.w};
    f32x2 dot = (uxv * X + uyv * Y) + uzv * Z;
    f32x2 spw = suv + Wp;
    f32x2 dd2 = dot * ntwo + spw;    // == rn(spw - 2*dot), product exact
    unsigned u0 = (__float_as_uint(dd2[0]) & 0xFFFFF000u) |
                  (0x00000FFFu & (unsigned)(j0 + 2 * k));
    float x0 = __uint_as_float(u0);
    KMIN4(Ka, Kb, Kc, Kd, x0);
    unsigned u1 = (__float_as_uint(dd2[1]) & 0xFFFFF000u) |
                  (0x00000FFFu & (unsigned)(j0 + 2 * k + 1));
    float x1 = __uint_as_float(u1);
    KMIN4(Ka, Kb, Kc, Kd, x1);
  }

  int q = b * N2 + n;
  keybuf[(ch * 4 + 0) * BQ + q] = Ka;
  keybuf[(ch * 4 + 1) * BQ + q] = Kb;
  keybuf[(ch * 4 + 2) * BQ + q] = Kc;
  keybuf[(ch * 4 + 3) * BQ + q] = Kd;
}

// ---------------------------------------------------------------------------
// k_merge: 4 lanes per query (512 blocks). Each lane folds 16 of the 64
// chunk keys, 2-round shfl_xor butterfly merges top-4s (set-min, order
// independent). Flag if global k3/k4 share masked value bits (the only case
// where keyed selection can differ from exact stable top-3); flagged queries
// take the exact (d,idx) LEXINS fallback. Weights from exact RN dd.
// ---------------------------------------------------------------------------
__global__ __launch_bounds__(256) void k_merge(
    const float* __restrict__ keybuf, const float4* __restrict__ pts4,
    const float* __restrict__ p2,
    float* __restrict__ wbuf, int* __restrict__ ibuf) {
#pragma clang fp contract(off)
  int tid = blockIdx.x * 256 + threadIdx.x;  // 512 blocks -> 131072 threads
  int sub = tid & 3;
  int q = tid >> 2;
  int b = q >> 14, n = q & (N2 - 1);

  const float* p2b = p2 + (size_t)b * 3 * N2;
  float ux = p2b[n], uy = p2b[N2 + n], uz = p2b[2 * N2 + n];
  float su = __fadd_rn(__fadd_rn(__fmul_rn(ux, ux), __fmul_rn(uy, uy)),
                       __fmul_rn(uz, uz));

  float Ka = 3.0e38f, Kb = 3.0e38f, Kc = 3.0e38f, Kd = 3.0e38f;
#pragma unroll 4
  for (int m = 0; m < 16; ++m) {
    float x = keybuf[(sub * 16 + m) * BQ + q];
    KMIN4(Ka, Kb, Kc, Kd, x);
  }
  // butterfly merge across the 4 sub-lanes
#pragma unroll
  for (int msk = 1; msk <= 2; msk <<= 1) {
    float ea = __shfl_xor(Ka, msk, 64), eb = __shfl_xor(Kb, msk, 64);
    float ec = __shfl_xor(Kc, msk, 64), ed = __shfl_xor(Kd, msk, 64);
    KMIN4(Ka, Kb, Kc, Kd, ea);
    KMIN4(Ka, Kb, Kc, Kd, eb);
    KMIN4(Ka, Kb, Kc, Kd, ec);
    KMIN4(Ka, Kb, Kc, Kd, ed);
  }
  if (sub != 0) return;

  bool flag = (__float_as_uint(Kc) >> 12) == (__float_as_uint(Kd) >> 12);
  const float4* pb = pts4 + (size_t)b * N1;
  float da, db, dc;
  int ia, ib, ic;
  if (!flag) {
    ia = (int)(__float_as_uint(Ka) & 0xFFFu);
    ib = (int)(__float_as_uint(Kb) & 0xFFFu);
    ic = (int)(__float_as_uint(Kc) & 0xFFFu);
    da = exact_dd(ux, uy, uz, su, pb[ia]);
    db = exact_dd(ux, uy, uz, su, pb[ib]);
    dc = exact_dd(ux, uy, uz, su, pb[ic]);
  } else {
    da = 3.0e38f; db = 3.0e38f; dc = 3.0e38f;
    ia = 0x7fffffff; ib = 0x7fffffff; ic = 0x7fffffff;
    for (int i = 0; i < 4 * NCH; ++i) {
      float x = keybuf[i * BQ + q];
      int jj = (int)(__float_as_uint(x) & 0xFFFu);
      float dd = exact_dd(ux, uy, uz, su, pb[jj]);
      LEXINS(da, db, dc, ia, ib, ic, dd, jj);
    }
  }

  float qa = fmaxf(da, 0.0f), qb = fmaxf(db, 0.0f), qc = fmaxf(dc, 0.0f);
  qa = fmaxf(__fmul_rn(qa, qa), 1e-10f);
  qb = fmaxf(__fmul_rn(qb, qb), 1e-10f);
  qc = fmaxf(__fmul_rn(qc, qc), 1e-10f);
  float va = __fdiv_rn(1.0f, qa);
  float vb = __fdiv_rn(1.0f, qb);
  float vc = __fdiv_rn(1.0f, qc);
  float s = __fadd_rn(__fadd_rn(va, vb), vc);
  wbuf[q]           = __fdiv_rn(va, s);
  wbuf[BQ + q]      = __fdiv_rn(vb, s);
  wbuf[2 * BQ + q]  = __fdiv_rn(vc, s);
  ibuf[q]          = ia;
  ibuf[BQ + q]     = ib;
  ibuf[2 * BQ + q] = ic;
}

// ---------------------------------------------------------------------------
// k_transpose: features1 [B,C1,N1] -> f1T [B,N1,C1].
// NOTE: f1T aliases keybuf — must launch after k_merge.
// ---------------------------------------------------------------------------
__global__ __launch_bounds__(256) void k_transpose(
    const float* __restrict__ f1, float* __restrict__ f1T) {
  __shared__ float tile[64][65];
  const int bx = blockIdx.x;            // B * 4(ct) * 64(nt) = 512
  const int b = bx >> 8;
  const int rest = bx & 255;
  const int ct = rest >> 6;
  const int ntb = (rest & 63) << 6;
  const int t = threadIdx.x;
  const int ln = t & 63, g = t >> 6;

  const float* src = f1 + ((size_t)b * C1 + ct * 64) * N1 + ntb;
  for (int k = 0; k < 16; ++k) {
    int c = (k << 2) + g;
    tile[c][ln] = src[(size_t)c * N1 + ln];
  }
  __syncthreads();
  float* dst = f1T + ((size_t)b * N1 + ntb) * C1 + ct * 64;
  for (int k = 0; k < 16; ++k) {
    int nn = (k << 2) + g;
    dst[(size_t)nn * C1 + ln] = tile[ln][nn];
  }
}

// ---------------------------------------------------------------------------
// k_fused: gather+interp -> bf16 LDS [col][k] -> MFMA GEMM1 -> BN1+ReLU ->
// bf16 LDS h -> MFMA GEMM2 -> BN2+ReLU -> out (fp32).
// 512 threads = 8 waves; wave wv owns 32 output rows; 64-col tile.
// 49KB LDS + 512 threads -> 3 blocks/CU = 24 waves/CU: Phase-A gather is
// 24 float4 loads/thread (was 48 at 256 threads) and latency is wave-hidden.
// Per-output arithmetic identical to the round-7 version.
// FIX vs round 8: Phase A1 covers all 64 float4 groups (m<8, idx4=qq*8+m);
// round 8 wrote only 16 of 64 -> poison in channels 64..255 -> inf.
// ---------------------------------------------------------------------------
__global__ __launch_bounds__(512) void k_fused(
    const float* __restrict__ f1T, const float* __restrict__ f2,
    const float* __restrict__ wbuf, const int* __restrict__ ibuf,
    const __bf16* __restrict__ W1b, const __bf16* __restrict__ W2b,
    const float* __restrict__ scsh, float* __restrict__ out) {
  __shared__ __bf16 sX[64 * KPAD];       // 49KB; x for GEMM1, then h for GEMM2
  const int t = threadIdx.x;
  const int bx = blockIdx.x;
  const int b = bx >> 8;
  const int n0 = (bx & 255) << 6;

  // ---- Phase A1: interp C1 channels (k = 0..255); 8 threads per column,
  //      8 float4 groups each (8*8 = 64 groups = 256 channels) ----
  {
    const int nn = t >> 3, qq = t & 7;
    const int gi = b * N2 + n0 + nn;
    const float w0 = wbuf[gi], w1 = wbuf[BQ + gi], w2 = wbuf[2 * BQ + gi];
    const int i0 = ibuf[gi], i1 = ibuf[BQ + gi], i2 = ibuf[2 * BQ + gi];
    const float4* r0 = (const float4*)(f1T + ((size_t)b * N1 + i0) * C1);
    const float4* r1 = (const float4*)(f1T + ((size_t)b * N1 + i1) * C1);
    const float4* r2 = (const float4*)(f1T + ((size_t)b * N1 + i2) * C1);
#pragma unroll 4
    for (int m = 0; m < 8; ++m) {
      int idx4 = (qq << 3) + m;          // 0..63
      float4 a = r0[idx4], c4 = r1[idx4], d4 = r2[idx4];
      bf16x4 v;
      v[0] = (__bf16)fmaf(w0, a.x, fmaf(w1, c4.x, w2 * d4.x));
      v[1] = (__bf16)fmaf(w0, a.y, fmaf(w1, c4.y, w2 * d4.y));
      v[2] = (__bf16)fmaf(w0, a.z, fmaf(w1, c4.z, w2 * d4.z));
      v[3] = (__bf16)fmaf(w0, a.w, fmaf(w1, c4.w, w2 * d4.w));
      *(bf16x4*)&sX[nn * KPAD + (idx4 << 2)] = v;
    }
  }
  // ---- Phase A2: features2 channels (k = 256..383); 8 groups of 16 ch ----
  {
    const int col = t & 63, g = t >> 6;
    const float* f2b = f2 + (size_t)b * C2 * N2 + n0 + col;
#pragma unroll
    for (int m = 0; m < 4; ++m) {
      int c4 = (g << 4) + (m << 2);
      bf16x4 v;
      v[0] = (__bf16)f2b[(size_t)(c4 + 0) * N2];
      v[1] = (__bf16)f2b[(size_t)(c4 + 1) * N2];
      v[2] = (__bf16)f2b[(size_t)(c4 + 2) * N2];
      v[3] = (__bf16)f2b[(size_t)(c4 + 3) * N2];
      *(bf16x4*)&sX[col * KPAD + 256 + c4] = v;
    }
  }
  __syncthreads();

  const int l  = t & 63;
  const int wv = __builtin_amdgcn_readfirstlane(t >> 6);
  const int ob = wv << 5;                // 32 rows per wave
  const int lm = l & 15, lg = l >> 4;

  f32x4 acc[2][4];
#pragma unroll
  for (int mt = 0; mt < 2; ++mt)
#pragma unroll
    for (int nt = 0; nt < 4; ++nt) acc[mt][nt] = (f32x4)0.0f;

  // ---- GEMM1: K = 384 (12 k-steps) ----
  for (int ks = 0; ks < 12; ++ks) {
    bf16x8 af[2], bfr[4];
#pragma unroll
    for (int mt = 0; mt < 2; ++mt)
      af[mt] = *(const bf16x8*)(W1b + (size_t)(ob + mt * 16 + lm) * K1 +
                                ks * 32 + lg * 8);
#pragma unroll
    for (int nt = 0; nt < 4; ++nt)
      bfr[nt] = *(const bf16x8*)&sX[(nt * 16 + lm) * KPAD + ks * 32 + lg * 8];
#pragma unroll
    for (int mt = 0; mt < 2; ++mt)
#pragma unroll
      for (int nt = 0; nt < 4; ++nt)
        acc[mt][nt] = __builtin_amdgcn_mfma_f32_16x16x32_bf16(
            af[mt], bfr[nt], acc[mt][nt], 0, 0, 0);
  }
  __syncthreads();

  // ---- BN1 + ReLU -> h (bf16) back into sX ----
#pragma unroll
  for (int mt = 0; mt < 2; ++mt) {
    int rb = ob + mt * 16 + lg * 4;     // h-channel base (GEMM1 output row)
    float4 sc4 = *(const float4*)(scsh + rb);
    float4 sh4 = *(const float4*)(scsh + HH + rb);
#pragma unroll
    for (int nt = 0; nt < 4; ++nt) {
      int colc = nt * 16 + lm;
      bf16x4 v;
      v[0] = (__bf16)fmaxf(fmaf(acc[mt][nt][0], sc4.x, sh4.x), 0.0f);
      v[1] = (__bf16)fmaxf(fmaf(acc[mt][nt][1], sc4.y, sh4.y), 0.0f);
      v[2] = (__bf16)fmaxf(fmaf(acc[mt][nt][2], sc4.z, sh4.z), 0.0f);
      v[3] = (__bf16)fmaxf(fmaf(acc[mt][nt][3], sc4.w, sh4.w), 0.0f);
      *(bf16x4*)&sX[colc * KPAD + rb] = v;
    }
  }
  __syncthreads();

  // ---- GEMM2: K = 256 (8 k-steps) ----
  f32x4 ac2[2][4];
#pragma unroll
  for (int mt = 0; mt < 2; ++mt)
#pragma unroll
    for (int nt = 0; nt < 4; ++nt) ac2[mt][nt] = (f32x4)0.0f;
  for (int ks = 0; ks < 8; ++ks) {
    bf16x8 af[2], bfr[4];
#pragma unroll
    for (int mt = 0; mt < 2; ++mt)
      af[mt] = *(const bf16x8*)(W2b + (size_t)(ob + mt * 16 + lm) * HH +
                                ks * 32 + lg * 8);
#pragma unroll
    for (int nt = 0; nt < 4; ++nt)
      bfr[nt] = *(const bf16x8*)&sX[(nt * 16 + lm) * KPAD + ks * 32 + lg * 8];
#pragma unroll
    for (int mt = 0; mt < 2; ++mt)
#pragma unroll
      for (int nt = 0; nt < 4; ++nt)
        ac2[mt][nt] = __builtin_amdgcn_mfma_f32_16x16x32_bf16(
            af[mt], bfr[nt], ac2[mt][nt], 0, 0, 0);
  }

  // ---- BN2 + ReLU -> out (fp32) ----
  float* outb = out + (size_t)b * HH * N2 + n0;
#pragma unroll
  for (int mt = 0; mt < 2; ++mt) {
    int rb = ob + mt * 16 + lg * 4;
    float4 sc4 = *(const float4*)(scsh + 2 * HH + rb);
    float4 sh4 = *(const float4*)(scsh + 3 * HH + rb);
#pragma unroll
    for (int nt = 0; nt < 4; ++nt) {
      int colc = nt * 16 + lm;
      outb[(size_t)(rb + 0) * N2 + colc] =
          fmaxf(fmaf(ac2[mt][nt][0], sc4.x, sh4.x), 0.0f);
      outb[(size_t)(rb + 1) * N2 + colc] =
          fmaxf(fmaf(ac2[mt][nt][1], sc4.y, sh4.y), 0.0f);
      outb[(size_t)(rb + 2) * N2 + colc] =
          fmaxf(fmaf(ac2[mt][nt][2], sc4.z, sh4.z), 0.0f);
      outb[(size_t)(rb + 3) * N2 + colc] =
          fmaxf(fmaf(ac2[mt][nt][3], sc4.w, sh4.w), 0.0f);
    }
  }
}

// ---------------------------------------------------------------------------
extern "C" void kernel_launch(void* const* d_in, const int* in_sizes, int n_in,
                              void* d_out, int out_size, void* d_ws, size_t ws_size,
                              hipStream_t stream) {
  const float* p1  = (const float*)d_in[0];
  const float* p2  = (const float*)d_in[1];
  const float* f1  = (const float*)d_in[2];
  const float* f2  = (const float*)d_in[3];
  const float* W1  = (const float*)d_in[4];
  const float* bb1 = (const float*)d_in[5];
  const float* g1  = (const float*)d_in[6];
  const float* be1 = (const float*)d_in[7];
  const float* mm1 = (const float*)d_in[8];
  const float* vv1 = (const float*)d_in[9];
  const float* W2  = (const float*)d_in[10];
  const float* bb2 = (const float*)d_in[11];
  const float* g2  = (const float*)d_in[12];
  const float* be2 = (const float*)d_in[13];
  const float* mm2 = (const float*)d_in[14];
  const float* vv2 = (const float*)d_in[15];
  float* out = (float*)d_out;

  // ws layout (~9.8 MB). keybuf lives only between k_nn and k_merge; the
  // same bytes are then reused for f1T (k_transpose launches after k_merge).
  char* ws = (char*)d_ws;
  float*  keybuf = (float*)(ws);                 // 8,388,608 B (= 64*BQ*4)
  float*  f1T    = (float*)(ws);                 // 8,388,608 B (alias)
  float*  wbuf   = (float*)(ws + 8388608);       //   393,216 B
  int*    ibuf   = (int*)  (ws + 8781824);       //   393,216 B
  float*  pts8   = (float*)(ws + 9175040);       //   131,072 B
  float4* pts4   = (float4*)(ws + 9306112);      //   131,072 B
  __bf16* W1b    = (__bf16*)(ws + 9437184);      //   196,608 B
  __bf16* W2b    = (__bf16*)(ws + 9633792);      //   131,072 B
  float*  scsh   = (float*)(ws + 9764864);       //     4,096 B

  k_prep<<<384, 256, 0, stream>>>(p1, W1, W2,
                                  bb1, g1, be1, mm1, vv1,
                                  bb2, g2, be2, mm2, vv2,
                                  pts8, pts4, W1b, W2b, scsh);
  k_nn<<<2048, 256, 0, stream>>>(p2, (const float4*)pts8, keybuf);
  k_merge<<<512, 256, 0, stream>>>(keybuf, pts4, p2, wbuf, ibuf);
  k_transpose<<<512, 256, 0, stream>>>(f1, f1T);   // reuses keybuf bytes
  k_fused<<<512, 512, 0, stream>>>(f1T, f2, wbuf, ibuf, W1b, W2b, scsh, out);
}

// Round 10
// 111.654 us; speedup vs baseline: 2.3291x; 1.1182x over previous
//
#include <hip/hip_runtime.h>
#include <cstdint>
#include <cstddef>

#define N1 4096
#define N2 16384
#define C1 256
#define C2 128
#define HH 256
#define K1 384
#define BQ 32768          // B*N2 total queries
#define KPAD 392          // LDS k-stride (bf16 elems): 16B-aligned, banks balanced
#define NCH 8             // k_nn point chunks (512 points each, 8KB LDS)

typedef float  f32x4  __attribute__((ext_vector_type(4)));
typedef float  f32x2  __attribute__((ext_vector_type(2)));
typedef __bf16 bf16x8 __attribute__((ext_vector_type(8)));
typedef __bf16 bf16x4 __attribute__((ext_vector_type(4)));

// Exact reference RN sequence for squared distance.
__device__ __forceinline__ float exact_dd(float ux, float uy, float uz,
                                          float su, float4 p) {
  float dot = __fadd_rn(__fadd_rn(__fmul_rn(ux, p.x), __fmul_rn(uy, p.y)),
                        __fmul_rn(uz, p.z));
  return __builtin_fmaf(dot, -2.0f, __fadd_rn(su, p.w));
}

// Lexicographic (d, idx) insert == stable top-k semantics (ties -> lower idx).
#define LEXINS(da, db, dc, ia, ib, ic, dd, jj)                                 \
  {                                                                            \
    bool ca = ((dd) < (da)) || ((dd) == (da) && (jj) < (ia));                  \
    bool cb = ((dd) < (db)) || ((dd) == (db) && (jj) < (ib));                  \
    bool cc = ((dd) < (dc)) || ((dd) == (dc) && (jj) < (ic));                  \
    dc = cb ? (db) : (cc ? (dd) : (dc));                                       \
    ic = cb ? (ib) : (cc ? (jj) : (ic));                                       \
    db = ca ? (da) : (cb ? (dd) : (db));                                       \
    ib = ca ? (ia) : (cb ? (jj) : (ib));                                       \
    da = ca ? (dd) : (da);                                                     \
    ia = ca ? (jj) : (ia);                                                     \
  }

// Sorted top-4 maintain on float keys: 1 min + 3 med3.
#define KMIN4(K1_, K2_, K3_, K4_, x)                                           \
  {                                                                            \
    float n1 = fminf((K1_), (x));                                              \
    float n2 = __builtin_amdgcn_fmed3f((K1_), (x), (K2_));                     \
    float n3 = __builtin_amdgcn_fmed3f((K2_), (x), (K3_));                     \
    float n4 = __builtin_amdgcn_fmed3f((K3_), (x), (K4_));                     \
    K1_ = n1; K2_ = n2; K3_ = n3; K4_ = n4;                                    \
  }

// ---------------------------------------------------------------------------
// k_prep: pts8 pair-SoA (pk math + LDS staging in k_nn) and plain pts4
// (gather in k_merge), exact RN |k|^2; W1/W2 -> bf16; BN folded.
// ---------------------------------------------------------------------------
__global__ __launch_bounds__(256) void k_prep(
    const float* __restrict__ p1,
    const float* __restrict__ W1, const float* __restrict__ W2,
    const float* __restrict__ b1, const float* __restrict__ g1,
    const float* __restrict__ be1, const float* __restrict__ mm1,
    const float* __restrict__ vv1,
    const float* __restrict__ b2, const float* __restrict__ g2,
    const float* __restrict__ be2, const float* __restrict__ mm2,
    const float* __restrict__ vv2,
    float* __restrict__ pts8, float4* __restrict__ pts4,
    __bf16* __restrict__ W1b, __bf16* __restrict__ W2b,
    float* __restrict__ scsh) {
  int idx = blockIdx.x * 256 + threadIdx.x;      // grid 384*256 = 98304
  if (idx < HH * K1) W1b[idx] = (__bf16)W1[idx];
  if (idx < HH * HH) W2b[idx] = (__bf16)W2[idx];
  if (idx < 2 * N1) {
    int b = idx >> 12, j = idx & (N1 - 1);
    const float* p = p1 + (size_t)b * 3 * N1;
    float x = p[j], y = p[N1 + j], z = p[2 * N1 + j];
    float sk = __fadd_rn(__fadd_rn(__fmul_rn(x, x), __fmul_rn(y, y)),
                         __fmul_rn(z, z));
    size_t base = ((size_t)b * (N1 / 2) + (j >> 1)) * 8 + (j & 1);
    pts8[base + 0] = x;
    pts8[base + 2] = y;
    pts8[base + 4] = z;
    pts8[base + 6] = sk;
    pts4[idx] = make_float4(x, y, z, sk);
  }
  if (idx < HH) {
    float sc = g1[idx] / sqrtf(vv1[idx] + 1e-3f);
    scsh[idx]          = sc;
    scsh[HH + idx]     = fmaf(b1[idx] - mm1[idx], sc, be1[idx]);
    float s2 = g2[idx] / sqrtf(vv2[idx] + 1e-3f);
    scsh[2 * HH + idx] = s2;
    scsh[3 * HH + idx] = fmaf(b2[idx] - mm2[idx], s2, be2[idx]);
  }
}

// ---------------------------------------------------------------------------
// k_nn: keyed brute-force 3-NN partials, LDS-staged points.
// 1024 blocks = 128 query-tiles x 8 chunks of 512 points (8KB LDS/block,
// 8 blocks/CU). Point reads are ds_read_b128 at immediate offsets from one
// base (no per-iter address VALU); uniform address -> broadcast, conflict
// free. Distance via v_pk ops: exact per-lane RN sequence of the reference
// (fma(dot,-2,spw) == rn(spw-2*dot), product exact). Key embeds the global
// point index in the low 12 bits (uniform literal OR).
// ---------------------------------------------------------------------------
__global__ __launch_bounds__(256) void k_nn(
    const float* __restrict__ p2, const float4* __restrict__ pts8v,
    float* __restrict__ keybuf) {
#pragma clang fp contract(off)
  __shared__ float4 spts[512];          // 256 pairs x 2 float4 = 8KB
  const int bx = blockIdx.x;
  const int ch = bx & (NCH - 1);
  const int qt = bx >> 3;            // 0..127
  const int b  = qt >> 6;            // uniform per block
  const int n  = ((qt & 63) << 8) + threadIdx.x;

  // stage chunk: 512 float4 in pair-SoA order
  {
    const float4* g = pts8v + (size_t)b * 4096 + ch * 512;
    spts[threadIdx.x]       = g[threadIdx.x];
    spts[threadIdx.x + 256] = g[threadIdx.x + 256];
  }

  const float* p2b = p2 + (size_t)b * 3 * N2;
  float ux = p2b[n], uy = p2b[N2 + n], uz = p2b[2 * N2 + n];
  float su = __fadd_rn(__fadd_rn(__fmul_rn(ux, ux), __fmul_rn(uy, uy)),
                       __fmul_rn(uz, uz));
  f32x2 uxv = {ux, ux}, uyv = {uy, uy}, uzv = {uz, uz}, suv = {su, su};
  const f32x2 ntwo = {-2.0f, -2.0f};
  __syncthreads();

  const int j0 = ch * 512;
  float Ka = 3.0e38f, Kb = 3.0e38f, Kc = 3.0e38f, Kd = 3.0e38f;
#pragma unroll 8
  for (int k = 0; k < 256; ++k) {
    float4 q0 = spts[2 * k];           // x0 x1 y0 y1
    float4 q1 = spts[2 * k + 1];       // z0 z1 w0 w1
    f32x2 X = {q0.x, q0.y}, Y = {q0.z, q0.w};
    f32x2 Z = {q1.x, q1.y}, Wp = {q1.z, q1.w};
    f32x2 dot = (uxv * X + uyv * Y) + uzv * Z;
    f32x2 spw = suv + Wp;
    f32x2 dd2 = __builtin_elementwise_fma(dot, ntwo, spw);
    unsigned u0 = (__float_as_uint(dd2[0]) & 0xFFFFF000u) |
                  (unsigned)(j0 + 2 * k);
    float x0 = __uint_as_float(u0);
    KMIN4(Ka, Kb, Kc, Kd, x0);
    unsigned u1 = (__float_as_uint(dd2[1]) & 0xFFFFF000u) |
                  (unsigned)(j0 + 2 * k + 1);
    float x1 = __uint_as_float(u1);
    KMIN4(Ka, Kb, Kc, Kd, x1);
  }

  int q = b * N2 + n;
  keybuf[(ch * 4 + 0) * BQ + q] = Ka;
  keybuf[(ch * 4 + 1) * BQ + q] = Kb;
  keybuf[(ch * 4 + 2) * BQ + q] = Kc;
  keybuf[(ch * 4 + 3) * BQ + q] = Kd;
}

// ---------------------------------------------------------------------------
// k_merge: 4 lanes per query (512 blocks). Each lane folds 8 of the 32
// chunk keys, 2-round shfl_xor butterfly merges top-4s (set-min, order
// independent). Flag if global k3/k4 share masked value bits (the only case
// where keyed selection can differ from exact stable top-3); flagged queries
// take the exact (d,idx) LEXINS fallback. Weights from exact RN dd.
// ---------------------------------------------------------------------------
__global__ __launch_bounds__(256) void k_merge(
    const float* __restrict__ keybuf, const float4* __restrict__ pts4,
    const float* __restrict__ p2,
    float* __restrict__ wbuf, int* __restrict__ ibuf) {
#pragma clang fp contract(off)
  int tid = blockIdx.x * 256 + threadIdx.x;  // 512 blocks -> 131072 threads
  int sub = tid & 3;
  int q = tid >> 2;
  int b = q >> 14, n = q & (N2 - 1);

  const float* p2b = p2 + (size_t)b * 3 * N2;
  float ux = p2b[n], uy = p2b[N2 + n], uz = p2b[2 * N2 + n];
  float su = __fadd_rn(__fadd_rn(__fmul_rn(ux, ux), __fmul_rn(uy, uy)),
                       __fmul_rn(uz, uz));

  float Ka = 3.0e38f, Kb = 3.0e38f, Kc = 3.0e38f, Kd = 3.0e38f;
#pragma unroll 4
  for (int m = 0; m < 8; ++m) {
    float x = keybuf[(sub * 8 + m) * BQ + q];
    KMIN4(Ka, Kb, Kc, Kd, x);
  }
  // butterfly merge across the 4 sub-lanes
#pragma unroll
  for (int msk = 1; msk <= 2; msk <<= 1) {
    float ea = __shfl_xor(Ka, msk, 64), eb = __shfl_xor(Kb, msk, 64);
    float ec = __shfl_xor(Kc, msk, 64), ed = __shfl_xor(Kd, msk, 64);
    KMIN4(Ka, Kb, Kc, Kd, ea);
    KMIN4(Ka, Kb, Kc, Kd, eb);
    KMIN4(Ka, Kb, Kc, Kd, ec);
    KMIN4(Ka, Kb, Kc, Kd, ed);
  }
  if (sub != 0) return;

  bool flag = (__float_as_uint(Kc) >> 12) == (__float_as_uint(Kd) >> 12);
  const float4* pb = pts4 + (size_t)b * N1;
  float da, db, dc;
  int ia, ib, ic;
  if (!flag) {
    ia = (int)(__float_as_uint(Ka) & 0xFFFu);
    ib = (int)(__float_as_uint(Kb) & 0xFFFu);
    ic = (int)(__float_as_uint(Kc) & 0xFFFu);
    da = exact_dd(ux, uy, uz, su, pb[ia]);
    db = exact_dd(ux, uy, uz, su, pb[ib]);
    dc = exact_dd(ux, uy, uz, su, pb[ic]);
  } else {
    da = 3.0e38f; db = 3.0e38f; dc = 3.0e38f;
    ia = 0x7fffffff; ib = 0x7fffffff; ic = 0x7fffffff;
    for (int i = 0; i < 4 * NCH; ++i) {
      float x = keybuf[i * BQ + q];
      int jj = (int)(__float_as_uint(x) & 0xFFFu);
      float dd = exact_dd(ux, uy, uz, su, pb[jj]);
      LEXINS(da, db, dc, ia, ib, ic, dd, jj);
    }
  }

  float qa = fmaxf(da, 0.0f), qb = fmaxf(db, 0.0f), qc = fmaxf(dc, 0.0f);
  qa = fmaxf(__fmul_rn(qa, qa), 1e-10f);
  qb = fmaxf(__fmul_rn(qb, qb), 1e-10f);
  qc = fmaxf(__fmul_rn(qc, qc), 1e-10f);
  float va = __fdiv_rn(1.0f, qa);
  float vb = __fdiv_rn(1.0f, qb);
  float vc = __fdiv_rn(1.0f, qc);
  float s = __fadd_rn(__fadd_rn(va, vb), vc);
  wbuf[q]           = __fdiv_rn(va, s);
  wbuf[BQ + q]      = __fdiv_rn(vb, s);
  wbuf[2 * BQ + q]  = __fdiv_rn(vc, s);
  ibuf[q]          = ia;
  ibuf[BQ + q]     = ib;
  ibuf[2 * BQ + q] = ic;
}

// ---------------------------------------------------------------------------
// k_transpose: features1 [B,C1,N1] -> f1T [B,N1,C1].
// NOTE: f1T aliases keybuf — must launch after k_merge.
// ---------------------------------------------------------------------------
__global__ __launch_bounds__(256) void k_transpose(
    const float* __restrict__ f1, float* __restrict__ f1T) {
  __shared__ float tile[64][65];
  const int bx = blockIdx.x;            // B * 4(ct) * 64(nt) = 512
  const int b = bx >> 8;
  const int rest = bx & 255;
  const int ct = rest >> 6;
  const int ntb = (rest & 63) << 6;
  const int t = threadIdx.x;
  const int ln = t & 63, g = t >> 6;

  const float* src = f1 + ((size_t)b * C1 + ct * 64) * N1 + ntb;
  for (int k = 0; k < 16; ++k) {
    int c = (k << 2) + g;
    tile[c][ln] = src[(size_t)c * N1 + ln];
  }
  __syncthreads();
  float* dst = f1T + ((size_t)b * N1 + ntb) * C1 + ct * 64;
  for (int k = 0; k < 16; ++k) {
    int nn = (k << 2) + g;
    dst[(size_t)nn * C1 + ln] = tile[ln][nn];
  }
}

// ---------------------------------------------------------------------------
// k_fused: gather+interp -> bf16 LDS [col][k] -> MFMA GEMM1 -> BN1+ReLU ->
// bf16 LDS h -> MFMA GEMM2 -> BN2+ReLU -> out (fp32).
// 512 threads = 8 waves; wave wv owns 32 output rows; 64-col tile.
// ---------------------------------------------------------------------------
__global__ __launch_bounds__(512) void k_fused(
    const float* __restrict__ f1T, const float* __restrict__ f2,
    const float* __restrict__ wbuf, const int* __restrict__ ibuf,
    const __bf16* __restrict__ W1b, const __bf16* __restrict__ W2b,
    const float* __restrict__ scsh, float* __restrict__ out) {
  __shared__ __bf16 sX[64 * KPAD];       // 49KB; x for GEMM1, then h for GEMM2
  const int t = threadIdx.x;
  const int bx = blockIdx.x;
  const int b = bx >> 8;
  const int n0 = (bx & 255) << 6;

  // ---- Phase A1: interp C1 channels; 8 threads/col x 8 float4 groups ----
  {
    const int nn = t >> 3, qq = t & 7;
    const int gi = b * N2 + n0 + nn;
    const float w0 = wbuf[gi], w1 = wbuf[BQ + gi], w2 = wbuf[2 * BQ + gi];
    const int i0 = ibuf[gi], i1 = ibuf[BQ + gi], i2 = ibuf[2 * BQ + gi];
    const float4* r0 = (const float4*)(f1T + ((size_t)b * N1 + i0) * C1);
    const float4* r1 = (const float4*)(f1T + ((size_t)b * N1 + i1) * C1);
    const float4* r2 = (const float4*)(f1T + ((size_t)b * N1 + i2) * C1);
#pragma unroll 4
    for (int m = 0; m < 8; ++m) {
      int idx4 = (qq << 3) + m;          // 0..63
      float4 a = r0[idx4], c4 = r1[idx4], d4 = r2[idx4];
      bf16x4 v;
      v[0] = (__bf16)fmaf(w0, a.x, fmaf(w1, c4.x, w2 * d4.x));
      v[1] = (__bf16)fmaf(w0, a.y, fmaf(w1, c4.y, w2 * d4.y));
      v[2] = (__bf16)fmaf(w0, a.z, fmaf(w1, c4.z, w2 * d4.z));
      v[3] = (__bf16)fmaf(w0, a.w, fmaf(w1, c4.w, w2 * d4.w));
      *(bf16x4*)&sX[nn * KPAD + (idx4 << 2)] = v;
    }
  }
  // ---- Phase A2: features2 channels (k = 256..383) ----
  {
    const int col = t & 63, g = t >> 6;
    const float* f2b = f2 + (size_t)b * C2 * N2 + n0 + col;
#pragma unroll
    for (int m = 0; m < 4; ++m) {
      int c4 = (g << 4) + (m << 2);
      bf16x4 v;
      v[0] = (__bf16)f2b[(size_t)(c4 + 0) * N2];
      v[1] = (__bf16)f2b[(size_t)(c4 + 1) * N2];
      v[2] = (__bf16)f2b[(size_t)(c4 + 2) * N2];
      v[3] = (__bf16)f2b[(size_t)(c4 + 3) * N2];
      *(bf16x4*)&sX[col * KPAD + 256 + c4] = v;
    }
  }
  __syncthreads();

  const int l  = t & 63;
  const int wv = __builtin_amdgcn_readfirstlane(t >> 6);
  const int ob = wv << 5;                // 32 rows per wave
  const int lm = l & 15, lg = l >> 4;

  f32x4 acc[2][4];
#pragma unroll
  for (int mt = 0; mt < 2; ++mt)
#pragma unroll
    for (int nt = 0; nt < 4; ++nt) acc[mt][nt] = (f32x4)0.0f;

  // ---- GEMM1: K = 384 (12 k-steps) ----
  for (int ks = 0; ks < 12; ++ks) {
    bf16x8 af[2], bfr[4];
#pragma unroll
    for (int mt = 0; mt < 2; ++mt)
      af[mt] = *(const bf16x8*)(W1b + (size_t)(ob + mt * 16 + lm) * K1 +
                                ks * 32 + lg * 8);
#pragma unroll
    for (int nt = 0; nt < 4; ++nt)
      bfr[nt] = *(const bf16x8*)&sX[(nt * 16 + lm) * KPAD + ks * 32 + lg * 8];
#pragma unroll
    for (int mt = 0; mt < 2; ++mt)
#pragma unroll
      for (int nt = 0; nt < 4; ++nt)
        acc[mt][nt] = __builtin_amdgcn_mfma_f32_16x16x32_bf16(
            af[mt], bfr[nt], acc[mt][nt], 0, 0, 0);
  }
  __syncthreads();

  // ---- BN1 + ReLU -> h (bf16) back into sX ----
#pragma unroll
  for (int mt = 0; mt < 2; ++mt) {
    int rb = ob + mt * 16 + lg * 4;     // h-channel base (GEMM1 output row)
    float4 sc4 = *(const float4*)(scsh + rb);
    float4 sh4 = *(const float4*)(scsh + HH + rb);
#pragma unroll
    for (int nt = 0; nt < 4; ++nt) {
      int colc = nt * 16 + lm;
      bf16x4 v;
      v[0] = (__bf16)fmaxf(fmaf(acc[mt][nt][0], sc4.x, sh4.x), 0.0f);
      v[1] = (__bf16)fmaxf(fmaf(acc[mt][nt][1], sc4.y, sh4.y), 0.0f);
      v[2] = (__bf16)fmaxf(fmaf(acc[mt][nt][2], sc4.z, sh4.z), 0.0f);
      v[3] = (__bf16)fmaxf(fmaf(acc[mt][nt][3], sc4.w, sh4.w), 0.0f);
      *(bf16x4*)&sX[colc * KPAD + rb] = v;
    }
  }
  __syncthreads();

  // ---- GEMM2: K = 256 (8 k-steps) ----
  f32x4 ac2[2][4];
#pragma unroll
  for (int mt = 0; mt < 2; ++mt)
#pragma unroll
    for (int nt = 0; nt < 4; ++nt) ac2[mt][nt] = (f32x4)0.0f;
  for (int ks = 0; ks < 8; ++ks) {
    bf16x8 af[2], bfr[4];
#pragma unroll
    for (int mt = 0; mt < 2; ++mt)
      af[mt] = *(const bf16x8*)(W2b + (size_t)(ob + mt * 16 + lm) * HH +
                                ks * 32 + lg * 8);
#pragma unroll
    for (int nt = 0; nt < 4; ++nt)
      bfr[nt] = *(const bf16x8*)&sX[(nt * 16 + lm) * KPAD + ks * 32 + lg * 8];
#pragma unroll
    for (int mt = 0; mt < 2; ++mt)
#pragma unroll
      for (int nt = 0; nt < 4; ++nt)
        ac2[mt][nt] = __builtin_amdgcn_mfma_f32_16x16x32_bf16(
            af[mt], bfr[nt], ac2[mt][nt], 0, 0, 0);
  }

  // ---- BN2 + ReLU -> out (fp32) ----
  float* outb = out + (size_t)b * HH * N2 + n0;
#pragma unroll
  for (int mt = 0; mt < 2; ++mt) {
    int rb = ob + mt * 16 + lg * 4;
    float4 sc4 = *(const float4*)(scsh + 2 * HH + rb);
    float4 sh4 = *(const float4*)(scsh + 3 * HH + rb);
#pragma unroll
    for (int nt = 0; nt < 4; ++nt) {
      int colc = nt * 16 + lm;
      outb[(size_t)(rb + 0) * N2 + colc] =
          fmaxf(fmaf(ac2[mt][nt][0], sc4.x, sh4.x), 0.0f);
      outb[(size_t)(rb + 1) * N2 + colc] =
          fmaxf(fmaf(ac2[mt][nt][1], sc4.y, sh4.y), 0.0f);
      outb[(size_t)(rb + 2) * N2 + colc] =
          fmaxf(fmaf(ac2[mt][nt][2], sc4.z, sh4.z), 0.0f);
      outb[(size_t)(rb + 3) * N2 + colc] =
          fmaxf(fmaf(ac2[mt][nt][3], sc4.w, sh4.w), 0.0f);
    }
  }
}

// ---------------------------------------------------------------------------
extern "C" void kernel_launch(void* const* d_in, const int* in_sizes, int n_in,
                              void* d_out, int out_size, void* d_ws, size_t ws_size,
                              hipStream_t stream) {
  const float* p1  = (const float*)d_in[0];
  const float* p2  = (const float*)d_in[1];
  const float* f1  = (const float*)d_in[2];
  const float* f2  = (const float*)d_in[3];
  const float* W1  = (const float*)d_in[4];
  const float* bb1 = (const float*)d_in[5];
  const float* g1  = (const float*)d_in[6];
  const float* be1 = (const float*)d_in[7];
  const float* mm1 = (const float*)d_in[8];
  const float* vv1 = (const float*)d_in[9];
  const float* W2  = (const float*)d_in[10];
  const float* bb2 = (const float*)d_in[11];
  const float* g2  = (const float*)d_in[12];
  const float* be2 = (const float*)d_in[13];
  const float* mm2 = (const float*)d_in[14];
  const float* vv2 = (const float*)d_in[15];
  float* out = (float*)d_out;

  // ws layout (~9.8 MB). keybuf (4.2MB) lives only between k_nn and k_merge;
  // f1T (8.4MB) reuses the same bytes (k_transpose launches after k_merge).
  char* ws = (char*)d_ws;
  float*  keybuf = (float*)(ws);                 // 4,194,304 B (= 32*BQ*4)
  float*  f1T    = (float*)(ws);                 // 8,388,608 B (alias)
  float*  wbuf   = (float*)(ws + 8388608);       //   393,216 B
  int*    ibuf   = (int*)  (ws + 8781824);       //   393,216 B
  float*  pts8   = (float*)(ws + 9175040);       //   131,072 B
  float4* pts4   = (float4*)(ws + 9306112);      //   131,072 B
  __bf16* W1b    = (__bf16*)(ws + 9437184);      //   196,608 B
  __bf16* W2b    = (__bf16*)(ws + 9633792);      //   131,072 B
  float*  scsh   = (float*)(ws + 9764864);       //     4,096 B

  k_prep<<<384, 256, 0, stream>>>(p1, W1, W2,
                                  bb1, g1, be1, mm1, vv1,
                                  bb2, g2, be2, mm2, vv2,
                                  pts8, pts4, W1b, W2b, scsh);
  k_nn<<<1024, 256, 0, stream>>>(p2, (const float4*)pts8, keybuf);
  k_merge<<<512, 256, 0, stream>>>(keybuf, pts4, p2, wbuf, ibuf);
  k_transpose<<<512, 256, 0, stream>>>(f1, f1T);   // reuses keybuf bytes
  k_fused<<<512, 512, 0, stream>>>(f1T, f2, wbuf, ibuf, W1b, W2b, scsh, out);
}